// Round 1
// baseline (1277.207 us; speedup 1.0000x reference)
//
#include <hip/hip_runtime.h>

#define B_ 8
#define C_ 128
#define H_ 64
#define W_ 64
#define O_ 128
#define F_ 18          // 2*K*K offset channels
#define K2_ 9
#define HW_ (H_*W_)    // 4096
#define CK2_ (C_*K2_)  // 1152

// ---------------- Kernel 1: offset = conv3x3(x, w_off) + b_off ----------------
// one thread per (b, ho, wo); 18 accumulators; x reads coalesced over wo,
// w_off reads wave-uniform (scalar-load path).
__global__ __launch_bounds__(256) void offset_conv_kernel(
    const float* __restrict__ x, const float* __restrict__ w_off,
    const float* __restrict__ b_off, float* __restrict__ offset) {
  int idx = blockIdx.x * blockDim.x + threadIdx.x;   // 0..32767
  int wo = idx & 63;
  int ho = (idx >> 6) & 63;
  int b  = idx >> 12;

  float acc[F_];
#pragma unroll
  for (int f = 0; f < F_; ++f) acc[f] = b_off[f];

  const float* xb = x + b * C_ * HW_;
  for (int c = 0; c < C_; ++c) {
    const float* xc = xb + c * HW_;
#pragma unroll
    for (int ky = 0; ky < 3; ++ky) {
      int y = ho - 1 + ky;
      if (y < 0 || y >= H_) continue;
#pragma unroll
      for (int kx = 0; kx < 3; ++kx) {
        int xw = wo - 1 + kx;
        if (xw < 0 || xw >= W_) continue;
        float xv = xc[y * W_ + xw];
        const float* wp = w_off + c * K2_ + ky * 3 + kx;  // + f*CK2_
#pragma unroll
        for (int f = 0; f < F_; ++f) acc[f] += xv * wp[f * CK2_];
      }
    }
  }
  float* op = offset + b * F_ * HW_ + ho * W_ + wo;
#pragma unroll
  for (int f = 0; f < F_; ++f) op[f * HW_] = acc[f];
}

// ---------------- Kernel 2: deformable sampling + channel contraction --------
// block = 256 threads, handles 8 consecutive spatial positions (same b, ho).
// Phase 1: samp[8][9][128] into LDS (36 KB). Phase 2: thread t owns
// o = t&127, positions (t>>7)*4 .. +3; per (c,k) one w load + 4 FMA with
// wave-uniform LDS broadcast reads.
__global__ __launch_bounds__(256) void deform_kernel(
    const float* __restrict__ x, const float* __restrict__ offset,
    const float* __restrict__ w, float* __restrict__ out) {
  __shared__ float samp[8 * K2_ * C_];   // 9216 floats = 36 KB

  int tid = threadIdx.x;
  int posBase = blockIdx.x * 8;          // global position = b*4096 + ho*64 + wo
  int b = posBase >> 12;

  // -------- phase 1: bilinear sampling --------
#pragma unroll
  for (int i = 0; i < 36; ++i) {
    int g = tid + i * 256;               // 0..9215
    int c = g & 127;
    int t = g >> 7;                      // p*9 + k  (uniform per wave)
    int k = t % 9;
    int p = t / 9;
    int posg = posBase + p;
    int wo = posg & 63;
    int ho = (posg >> 6) & 63;

    const float* offb = offset + b * F_ * HW_ + ho * W_ + wo;
    float oy = offb[(2 * k) * HW_];
    float ox = offb[(2 * k + 1) * HW_];
    float py = (float)(ho - 1 + k / 3) + oy;
    float px = (float)(wo - 1 + k % 3) + ox;
    float y0f = floorf(py), x0f = floorf(px);
    float dy = py - y0f, dx = px - x0f;
    int y0 = (int)y0f, x0 = (int)x0f;

    const float* xc = x + (b * C_ + c) * HW_;
    float v00 = 0.f, v01 = 0.f, v10 = 0.f, v11 = 0.f;
    bool yv0 = (y0 >= 0) & (y0 < H_);
    bool yv1 = (y0 + 1 >= 0) & (y0 + 1 < H_);
    bool xv0 = (x0 >= 0) & (x0 < W_);
    bool xv1 = (x0 + 1 >= 0) & (x0 + 1 < W_);
    if (yv0 && xv0) v00 = xc[y0 * W_ + x0];
    if (yv0 && xv1) v01 = xc[y0 * W_ + x0 + 1];
    if (yv1 && xv0) v10 = xc[(y0 + 1) * W_ + x0];
    if (yv1 && xv1) v11 = xc[(y0 + 1) * W_ + x0 + 1];

    float s = v00 * (1.f - dy) * (1.f - dx) + v01 * (1.f - dy) * dx +
              v10 * dy * (1.f - dx) + v11 * dy * dx;
    samp[t * C_ + c] = s;
  }
  __syncthreads();

  // -------- phase 2: out[b,o,pos] = sum_{c,k} samp[p][k][c] * w[o][c][k] ----
  int o  = tid & 127;
  int ph = tid >> 7;                     // 0 or 1 (uniform per wave)
  float acc0 = 0.f, acc1 = 0.f, acc2 = 0.f, acc3 = 0.f;
  const float* wp = w + o * CK2_;
  for (int c = 0; c < C_; ++c) {
#pragma unroll
    for (int k = 0; k < 9; ++k) {
      float wv = wp[c * 9 + k];
      int sbase = k * C_ + c;
      acc0 += wv * samp[(ph * 4 + 0) * K2_ * C_ + sbase];
      acc1 += wv * samp[(ph * 4 + 1) * K2_ * C_ + sbase];
      acc2 += wv * samp[(ph * 4 + 2) * K2_ * C_ + sbase];
      acc3 += wv * samp[(ph * 4 + 3) * K2_ * C_ + sbase];
    }
  }
  float accs[4] = {acc0, acc1, acc2, acc3};
#pragma unroll
  for (int j = 0; j < 4; ++j) {
    int posg = posBase + ph * 4 + j;
    int wo2 = posg & 63;
    int ho2 = (posg >> 6) & 63;
    out[(b * O_ + o) * HW_ + ho2 * W_ + wo2] = accs[j];
  }
}

extern "C" void kernel_launch(void* const* d_in, const int* in_sizes, int n_in,
                              void* d_out, int out_size, void* d_ws, size_t ws_size,
                              hipStream_t stream) {
  const float* x     = (const float*)d_in[0];
  const float* w_off = (const float*)d_in[1];
  const float* b_off = (const float*)d_in[2];
  const float* w     = (const float*)d_in[3];
  float* out = (float*)d_out;
  float* offset = (float*)d_ws;          // B*18*64*64 floats = 2.36 MB

  // Kernel 1: 8*64*64 = 32768 positions
  offset_conv_kernel<<<32768 / 256, 256, 0, stream>>>(x, w_off, b_off, offset);

  // Kernel 2: 32768 positions / 8 per block = 4096 blocks
  deform_kernel<<<4096, 256, 0, stream>>>(x, offset, w, out);
}

// Round 2
// 411.533 us; speedup vs baseline: 3.1035x; 3.1035x over previous
//
#include <hip/hip_runtime.h>

#define B_ 8
#define C_ 128
#define H_ 64
#define W_ 64
#define O_ 128
#define F_ 18
#define K2_ 9
#define HW_ (H_*W_)      // 4096
#define CK2_ (C_*K2_)    // 1152

typedef __attribute__((ext_vector_type(8))) short short8_t;   // 8 bf16 = 4 VGPRs
typedef __attribute__((ext_vector_type(4))) float f32x4_t;

__device__ inline short bf16r(float f) {
  unsigned u = __builtin_bit_cast(unsigned, f);
  u += 0x7FFFu + ((u >> 16) & 1u);     // round-to-nearest-even
  return (short)(u >> 16);
}

// ---------------- Kernel 0: repack w -> bf16 w_bt[o][kk], kk = tap*128 + c ---
__global__ __launch_bounds__(256) void prep_w_kernel(
    const float* __restrict__ w, short* __restrict__ w_bt) {
  int i = blockIdx.x * 256 + threadIdx.x;      // 0 .. 147455
  if (i >= O_ * CK2_) return;
  int o = i / CK2_, r = i % CK2_;
  int kt = r >> 7, c = r & 127;
  w_bt[i] = bf16r(w[(o * C_ + c) * K2_ + kt]);
}

// ---------------- Kernel 1: offset = conv3x3(x, w_off) + b_off (fp32) --------
__global__ __launch_bounds__(256) void offset_conv_kernel(
    const float* __restrict__ x, const float* __restrict__ w_off,
    const float* __restrict__ b_off, float* __restrict__ offset) {
  int idx = blockIdx.x * blockDim.x + threadIdx.x;   // 0..32767
  int wo = idx & 63;
  int ho = (idx >> 6) & 63;
  int b  = idx >> 12;

  float acc[F_];
#pragma unroll
  for (int f = 0; f < F_; ++f) acc[f] = b_off[f];

  const float* xb = x + b * C_ * HW_;
  for (int c = 0; c < C_; ++c) {
    const float* xc = xb + c * HW_;
#pragma unroll
    for (int ky = 0; ky < 3; ++ky) {
      int y = ho - 1 + ky;
      if (y < 0 || y >= H_) continue;
#pragma unroll
      for (int kx = 0; kx < 3; ++kx) {
        int xw = wo - 1 + kx;
        if (xw < 0 || xw >= W_) continue;
        float xv = xc[y * W_ + xw];
        const float* wp = w_off + c * K2_ + ky * 3 + kx;
#pragma unroll
        for (int f = 0; f < F_; ++f) acc[f] += xv * wp[f * CK2_];
      }
    }
  }
  float* op = offset + b * F_ * HW_ + ho * W_ + wo;
#pragma unroll
  for (int f = 0; f < F_; ++f) op[f * HW_] = acc[f];
}

// ---------------- Kernel 2: deformable sampling + MFMA contraction ----------
// 1 wave / block. Block owns 16 consecutive positions (same b, ho).
// GEMM: D[o=128][pos=16] += W[o][K=1152] * S[K][pos], K = tap*128 + c.
// A-operand (arg0) = w fragments: lane row (l&15) = o%16, k = (l>>4)*8+j.
// B-operand (arg1) = sample fragments: lane col (l&15) = pos, k = (l>>4)*8+j.
// D: row (o sub) = (l>>4)*4 + reg, col = l&15 = pos -> coalesced stores.
__global__ __launch_bounds__(64) void deform_mfma_kernel(
    const float* __restrict__ x, const float* __restrict__ offset,
    const short* __restrict__ w_bt, float* __restrict__ out) {
  int tid = threadIdx.x;
  int fr = tid & 15;          // A: o%16 ; B: pos index ; D: pos index
  int q  = tid >> 4;          // k-chunk selector
  int pos_base = blockIdx.x << 4;
  int b  = pos_base >> 12;
  int ho = (pos_base >> 6) & 63;
  int wo_base = pos_base & 63;
  int wo = wo_base + fr;

  f32x4_t acc[8];
#pragma unroll
  for (int nf = 0; nf < 8; ++nf) acc[nf] = (f32x4_t){0.f, 0.f, 0.f, 0.f};

  const float* xb   = x + ((long)b * C_ * HW_);
  const float* offb = offset + ((long)b * F_ * HW_) + (ho << 6) + wo;

  for (int kt = 0; kt < 9; ++kt) {
    float oy = offb[(2 * kt) * HW_];
    float ox = offb[(2 * kt + 1) * HW_];
    float py = (float)(ho + (kt / 3) - 1) + oy;
    float px = (float)(wo + (kt % 3) - 1) + ox;
    float fy0 = floorf(py), fx0 = floorf(px);
    float dy = py - fy0, dx = px - fx0;
    int y0 = (int)fy0, x0 = (int)fx0;
    int y1 = y0 + 1, x1 = x0 + 1;
    float my0 = (y0 >= 0 && y0 < H_) ? 1.f : 0.f;
    float my1 = (y1 >= 0 && y1 < H_) ? 1.f : 0.f;
    float mx0 = (x0 >= 0 && x0 < W_) ? 1.f : 0.f;
    float mx1 = (x1 >= 0 && x1 < W_) ? 1.f : 0.f;
    float w00 = (1.f - dy) * (1.f - dx) * my0 * mx0;
    float w01 = (1.f - dy) * dx * my0 * mx1;
    float w10 = dy * (1.f - dx) * my1 * mx0;
    float w11 = dy * dx * my1 * mx1;
    int y0c = min(max(y0, 0), H_ - 1), y1c = min(max(y1, 0), H_ - 1);
    int x0c = min(max(x0, 0), W_ - 1), x1c = min(max(x1, 0), W_ - 1);
    int o00 = (y0c << 6) + x0c, o01 = (y0c << 6) + x1c;
    int o10 = (y1c << 6) + x0c, o11 = (y1c << 6) + x1c;

#pragma unroll
    for (int s = 0; s < 4; ++s) {
      short8_t sf;
#pragma unroll
      for (int j = 0; j < 8; ++j) {
        const float* xp = xb + (((s << 5) + (q << 3) + j) << 12);
        float v = w00 * xp[o00] + w01 * xp[o01] + w10 * xp[o10] + w11 * xp[o11];
        sf[j] = bf16r(v);
      }
      int kk = kt * 128 + (s << 5) + (q << 3);
      const short* wp = w_bt + fr * CK2_ + kk;
#pragma unroll
      for (int nf = 0; nf < 8; ++nf) {
        short8_t wf = *(const short8_t*)(wp + nf * 16 * CK2_);
        acc[nf] = __builtin_amdgcn_mfma_f32_16x16x32_bf16(wf, sf, acc[nf], 0, 0, 0);
      }
    }
  }

  // epilogue: D[o][pos], o = nf*16 + q*4 + r, pos col = fr -> coalesced
  float* ob = out + ((long)b * O_ * HW_) + (ho << 6) + wo_base + fr;
#pragma unroll
  for (int nf = 0; nf < 8; ++nf) {
#pragma unroll
    for (int r = 0; r < 4; ++r) {
      ob[(((nf << 4) + (q << 2) + r) << 12)] = acc[nf][r];
    }
  }
}

extern "C" void kernel_launch(void* const* d_in, const int* in_sizes, int n_in,
                              void* d_out, int out_size, void* d_ws, size_t ws_size,
                              hipStream_t stream) {
  const float* x     = (const float*)d_in[0];
  const float* w_off = (const float*)d_in[1];
  const float* b_off = (const float*)d_in[2];
  const float* w     = (const float*)d_in[3];
  float* out = (float*)d_out;

  float* offset = (float*)d_ws;                          // 8*18*4096 f32 = 2.36 MB
  short* w_bt   = (short*)((char*)d_ws + (size_t)B_ * F_ * HW_ * sizeof(float));

  prep_w_kernel<<<(O_ * CK2_ + 255) / 256, 256, 0, stream>>>(w, w_bt);
  offset_conv_kernel<<<(B_ * HW_) / 256, 256, 0, stream>>>(x, w_off, b_off, offset);
  deform_mfma_kernel<<<(B_ * HW_) / 16, 64, 0, stream>>>(x, offset, w_bt, out);
}

// Round 3
// 233.202 us; speedup vs baseline: 5.4768x; 1.7647x over previous
//
#include <hip/hip_runtime.h>

#define B_ 8
#define C_ 128
#define H_ 64
#define W_ 64
#define O_ 128
#define F_ 18
#define K2_ 9
#define HW_ (H_*W_)      // 4096
#define CK2_ (C_*K2_)    // 1152

typedef __attribute__((ext_vector_type(8))) short short8_t;   // 8 bf16 = 4 VGPRs
typedef __attribute__((ext_vector_type(4))) float f32x4_t;

__device__ inline short bf16r(float f) {
  unsigned u = __builtin_bit_cast(unsigned, f);
  u += 0x7FFFu + ((u >> 16) & 1u);     // round-to-nearest-even
  return (short)(u >> 16);
}

// -------- Kernel 0a: repack w -> bf16 w_bt[o][kk], kk = tap*128 + c ---------
__global__ __launch_bounds__(256) void prep_w_kernel(
    const float* __restrict__ w, short* __restrict__ w_bt) {
  int i = blockIdx.x * 256 + threadIdx.x;      // 0 .. 147455
  if (i >= O_ * CK2_) return;
  int o = i / CK2_, r = i % CK2_;
  int kt = r >> 7, c = r & 127;
  w_bt[i] = bf16r(w[(o * C_ + c) * K2_ + kt]);
}

// -------- Kernel 0b: repack w_off -> bf16 w_ot[32][kk], kk = tap*128 + c ----
// rows 18..31 zero-padded (second M-tile of the offset-conv GEMM).
__global__ __launch_bounds__(256) void prep_woff_kernel(
    const float* __restrict__ w_off, short* __restrict__ w_ot) {
  int i = blockIdx.x * 256 + threadIdx.x;      // 0 .. 36863
  if (i >= 32 * CK2_) return;
  int f = i / CK2_, r = i % CK2_;
  int kt = r >> 7, c = r & 127;
  w_ot[i] = (f < F_) ? bf16r(w_off[f * CK2_ + c * K2_ + kt]) : (short)0;
}

// -------- Kernel 1: fused offset-conv (MFMA) + deform sampling + GEMM -------
// 1 wave / block, 16 consecutive positions (same b, ho).
// Phase A: offs[f=18][pos=16] = W_off * Xtaps  (2 M-tiles x 36 K-steps) -> LDS
// Phase B: bilinear sampling from x (register B-fragments) + 8-tile GEMM
//          D[o=128][pos=16] += W[o][K=1152] * S[K][pos], K = tap*128 + c.
__global__ __launch_bounds__(64) void fused_deform_kernel(
    const float* __restrict__ x, const short* __restrict__ w_ot,
    const float* __restrict__ b_off, const short* __restrict__ w_bt,
    float* __restrict__ out) {
  __shared__ float offs[16][20];               // [pos][f], padded

  int tid = threadIdx.x;
  int fr = tid & 15;          // A: row sub ; B/D: position column
  int q  = tid >> 4;          // k-chunk selector
  int pos_base = blockIdx.x << 4;
  int b  = pos_base >> 12;
  int ho = (pos_base >> 6) & 63;
  int wo_base = pos_base & 63;
  int wo = wo_base + fr;

  const float* xb = x + ((long)b * C_ * HW_);

  // ---------------- Phase A: offset conv via MFMA ----------------
  {
    f32x4_t oacc0 = (f32x4_t){0.f, 0.f, 0.f, 0.f};
    f32x4_t oacc1 = (f32x4_t){0.f, 0.f, 0.f, 0.f};
    for (int kt = 0; kt < 9; ++kt) {
      int y  = ho + kt / 3 - 1;
      int xx = wo + kt % 3 - 1;
      bool yok = (y >= 0) & (y < H_);
      bool xok = (xx >= 0) & (xx < W_);
      int xoff = (y << 6) + xx;
#pragma unroll
      for (int s = 0; s < 4; ++s) {
        int c0 = (s << 5) + (q << 3);
        short8_t bf;
#pragma unroll
        for (int j = 0; j < 8; ++j) {
          float v = (yok && xok) ? xb[((c0 + j) << 12) + xoff] : 0.f;
          bf[j] = bf16r(v);
        }
        int kk = kt * 128 + c0;
        short8_t a0 = *(const short8_t*)(w_ot + fr * CK2_ + kk);
        short8_t a1 = *(const short8_t*)(w_ot + (16 + fr) * CK2_ + kk);
        oacc0 = __builtin_amdgcn_mfma_f32_16x16x32_bf16(a0, bf, oacc0, 0, 0, 0);
        oacc1 = __builtin_amdgcn_mfma_f32_16x16x32_bf16(a1, bf, oacc1, 0, 0, 0);
      }
    }
    // D[f][pos]: col = fr (pos), row f = q*4 + r (tile0) / 16+q*4+r (tile1)
#pragma unroll
    for (int r = 0; r < 4; ++r) {
      int f0 = (q << 2) + r;
      offs[fr][f0] = oacc0[r] + b_off[f0];
    }
    if (q == 0) {
      offs[fr][16] = oacc1[0] + b_off[16];
      offs[fr][17] = oacc1[1] + b_off[17];
    }
  }
  __syncthreads();

  // ---------------- Phase B: sampling + main GEMM ----------------
  f32x4_t acc[8];
#pragma unroll
  for (int nf = 0; nf < 8; ++nf) acc[nf] = (f32x4_t){0.f, 0.f, 0.f, 0.f};

  for (int kt = 0; kt < 9; ++kt) {
    float oy = offs[fr][2 * kt];
    float ox = offs[fr][2 * kt + 1];
    float py = (float)(ho + (kt / 3) - 1) + oy;
    float px = (float)(wo + (kt % 3) - 1) + ox;
    float fy0 = floorf(py), fx0 = floorf(px);
    float dy = py - fy0, dx = px - fx0;
    int y0 = (int)fy0, x0 = (int)fx0;
    int y1 = y0 + 1, x1 = x0 + 1;
    float my0 = (y0 >= 0 && y0 < H_) ? 1.f : 0.f;
    float my1 = (y1 >= 0 && y1 < H_) ? 1.f : 0.f;
    float mx0 = (x0 >= 0 && x0 < W_) ? 1.f : 0.f;
    float mx1 = (x1 >= 0 && x1 < W_) ? 1.f : 0.f;
    float w00 = (1.f - dy) * (1.f - dx) * my0 * mx0;
    float w01 = (1.f - dy) * dx * my0 * mx1;
    float w10 = dy * (1.f - dx) * my1 * mx0;
    float w11 = dy * dx * my1 * mx1;
    int y0c = min(max(y0, 0), H_ - 1), y1c = min(max(y1, 0), H_ - 1);
    int x0c = min(max(x0, 0), W_ - 1), x1c = min(max(x1, 0), W_ - 1);
    int o00 = (y0c << 6) + x0c, o01 = (y0c << 6) + x1c;
    int o10 = (y1c << 6) + x0c, o11 = (y1c << 6) + x1c;

#pragma unroll
    for (int s = 0; s < 4; ++s) {
      short8_t sf;
#pragma unroll
      for (int j = 0; j < 8; ++j) {
        const float* xp = xb + (((s << 5) + (q << 3) + j) << 12);
        float v = w00 * xp[o00] + w01 * xp[o01] + w10 * xp[o10] + w11 * xp[o11];
        sf[j] = bf16r(v);
      }
      int kk = kt * 128 + (s << 5) + (q << 3);
      const short* wp = w_bt + fr * CK2_ + kk;
#pragma unroll
      for (int nf = 0; nf < 8; ++nf) {
        short8_t wf = *(const short8_t*)(wp + nf * 16 * CK2_);
        acc[nf] = __builtin_amdgcn_mfma_f32_16x16x32_bf16(wf, sf, acc[nf], 0, 0, 0);
      }
    }
  }

  // epilogue: D[o][pos], o = nf*16 + q*4 + r, pos col = fr -> coalesced
  float* ob = out + ((long)b * O_ * HW_) + (ho << 6) + wo_base + fr;
#pragma unroll
  for (int nf = 0; nf < 8; ++nf) {
#pragma unroll
    for (int r = 0; r < 4; ++r) {
      ob[(((nf << 4) + (q << 2) + r) << 12)] = acc[nf][r];
    }
  }
}

extern "C" void kernel_launch(void* const* d_in, const int* in_sizes, int n_in,
                              void* d_out, int out_size, void* d_ws, size_t ws_size,
                              hipStream_t stream) {
  const float* x     = (const float*)d_in[0];
  const float* w_off = (const float*)d_in[1];
  const float* b_off = (const float*)d_in[2];
  const float* w     = (const float*)d_in[3];
  float* out = (float*)d_out;

  short* w_bt = (short*)d_ws;                                  // 128*1152*2 B
  short* w_ot = (short*)((char*)d_ws + (size_t)O_ * CK2_ * 2); // 32*1152*2 B

  prep_w_kernel<<<(O_ * CK2_ + 255) / 256, 256, 0, stream>>>(w, w_bt);
  prep_woff_kernel<<<(32 * CK2_ + 255) / 256, 256, 0, stream>>>(w_off, w_ot);
  fused_deform_kernel<<<(B_ * HW_) / 16, 64, 0, stream>>>(x, w_ot, b_off, w_bt, out);
}

// Round 4
// 139.070 us; speedup vs baseline: 9.1839x; 1.6769x over previous
//
#include <hip/hip_runtime.h>

#define B_ 8
#define C_ 128
#define H_ 64
#define W_ 64
#define O_ 128
#define F_ 18
#define K2_ 9
#define HW_ 4096
#define CK2_ 1152

typedef __attribute__((ext_vector_type(8))) short short8_t;   // 8 bf16
typedef __attribute__((ext_vector_type(4))) float f32x4_t;

__device__ inline short bf16r(float f) {
  unsigned u = __builtin_bit_cast(unsigned, f);
  u += 0x7FFFu + ((u >> 16) & 1u);     // round-to-nearest-even
  return (short)(u >> 16);
}
__device__ inline float bf2f(short s) {
  unsigned u = ((unsigned)(unsigned short)s) << 16;
  return __builtin_bit_cast(float, u);
}

// -------- Kernel 0a: repack w -> bf16 w_bt[o][kk], kk = tap*128 + c ---------
__global__ __launch_bounds__(256) void prep_w_kernel(
    const float* __restrict__ w, short* __restrict__ w_bt) {
  int i = blockIdx.x * 256 + threadIdx.x;
  if (i >= O_ * CK2_) return;
  int o = i / CK2_, r = i % CK2_;
  int kt = r >> 7, c = r & 127;
  w_bt[i] = bf16r(w[(o * C_ + c) * K2_ + kt]);
}

// -------- Kernel 0b: repack w_off -> bf16 w_ot[32][kk] (rows 18..31 zero) ---
__global__ __launch_bounds__(256) void prep_woff_kernel(
    const float* __restrict__ w_off, short* __restrict__ w_ot) {
  int i = blockIdx.x * 256 + threadIdx.x;
  if (i >= 32 * CK2_) return;
  int f = i / CK2_, r = i % CK2_;
  int kt = r >> 7, c = r & 127;
  w_ot[i] = (f < F_) ? bf16r(w_off[f * CK2_ + c * K2_ + kt]) : (short)0;
}

// -------- Kernel 0c: x (NCHW f32) -> x_t[b][y][x][c] bf16 (channels-last) ---
__global__ __launch_bounds__(256) void prep_xt_kernel(
    const float* __restrict__ x, short* __restrict__ x_t) {
  __shared__ float tile[128][65];      // padded: stride 65 kills bank conflicts
  int t = threadIdx.x;
  int b = blockIdx.x >> 6;             // 512 blocks: 8 b x 64 pixel-tiles
  int p_base = (blockIdx.x & 63) << 6; // 64 pixels per tile
  const float* xb = x + ((long)b << 19);
#pragma unroll
  for (int i = 0; i < 32; ++i) {
    int idx = (i << 8) + t;
    int c = idx >> 6, p = idx & 63;    // coalesced read: 64 consecutive floats
    tile[c][p] = xb[((long)c << 12) + p_base + p];
  }
  __syncthreads();
#pragma unroll
  for (int i = 0; i < 32; ++i) {
    int idx = (i << 8) + t;
    int p = idx >> 7, c = idx & 127;   // coalesced write: 128 consecutive shorts
    x_t[(((long)(b << 12) + p_base + p) << 7) + c] = bf16r(tile[c][p]);
  }
}

// -------- Kernel 1: fused offset-conv (MFMA) + deform sampling + GEMM -------
// 1 wave / block, 16 consecutive positions (same b, ho). XCD-swizzled so each
// XCD owns one batch (L2-resident working set ~1.5 MB).
__global__ __launch_bounds__(64) void fused_deform_kernel(
    const short* __restrict__ x_t, const short* __restrict__ w_ot,
    const float* __restrict__ b_off, const short* __restrict__ w_bt,
    float* __restrict__ out) {
  __shared__ float offs[16][20];

  int tid = threadIdx.x;
  int fr = tid & 15;          // A: row sub ; B/D: position column
  int q  = tid >> 4;          // k-chunk selector
  int bid = (int)blockIdx.x;
  int swz = ((bid & 7) << 8) + (bid >> 3);   // XCD k <- batch k (2048 = 8*256)
  int pos_base = swz << 4;
  int b  = pos_base >> 12;
  int ho = (pos_base >> 6) & 63;
  int wo_base = pos_base & 63;
  int wo = wo_base + fr;

  const short* xtb = x_t + ((long)b << 19);  // 4096 pixels * 128 c

  // ---------------- Phase A: offset conv via MFMA ----------------
  {
    f32x4_t oacc0 = (f32x4_t){0.f, 0.f, 0.f, 0.f};
    f32x4_t oacc1 = (f32x4_t){0.f, 0.f, 0.f, 0.f};
    for (int kt = 0; kt < 9; ++kt) {
      int y  = ho + kt / 3 - 1;
      int xx = wo + kt % 3 - 1;
      bool ok = (y >= 0) & (y < H_) & (xx >= 0) & (xx < W_);
      int yc = min(max(y, 0), H_ - 1), xc = min(max(xx, 0), W_ - 1);
      const short* px = xtb + (((yc << 6) + xc) << 7);
#pragma unroll
      for (int s = 0; s < 4; ++s) {
        int c0 = (s << 5) + (q << 3);
        short8_t bfv = *(const short8_t*)(px + c0);
        if (!ok) bfv = (short8_t){0, 0, 0, 0, 0, 0, 0, 0};
        int kk = kt * 128 + c0;
        short8_t a0 = *(const short8_t*)(w_ot + fr * CK2_ + kk);
        short8_t a1 = *(const short8_t*)(w_ot + (16 + fr) * CK2_ + kk);
        oacc0 = __builtin_amdgcn_mfma_f32_16x16x32_bf16(a0, bfv, oacc0, 0, 0, 0);
        oacc1 = __builtin_amdgcn_mfma_f32_16x16x32_bf16(a1, bfv, oacc1, 0, 0, 0);
      }
    }
#pragma unroll
    for (int r = 0; r < 4; ++r) {
      int f0 = (q << 2) + r;
      offs[fr][f0] = oacc0[r] + b_off[f0];
    }
    if (q == 0) {
      offs[fr][16] = oacc1[0] + b_off[16];
      offs[fr][17] = oacc1[1] + b_off[17];
    }
  }
  __syncthreads();

  // ---------------- Phase B: sampling + main GEMM ----------------
  f32x4_t acc[8];
#pragma unroll
  for (int nf = 0; nf < 8; ++nf) acc[nf] = (f32x4_t){0.f, 0.f, 0.f, 0.f};

  for (int kt = 0; kt < 9; ++kt) {
    float oy = offs[fr][2 * kt];
    float ox = offs[fr][2 * kt + 1];
    float py = (float)(ho + (kt / 3) - 1) + oy;
    float px = (float)(wo + (kt % 3) - 1) + ox;
    float fy0 = floorf(py), fx0 = floorf(px);
    float dy = py - fy0, dx = px - fx0;
    int y0 = (int)fy0, x0 = (int)fx0;
    int y1 = y0 + 1, x1 = x0 + 1;
    float my0 = (y0 >= 0 && y0 < H_) ? 1.f : 0.f;
    float my1 = (y1 >= 0 && y1 < H_) ? 1.f : 0.f;
    float mx0 = (x0 >= 0 && x0 < W_) ? 1.f : 0.f;
    float mx1 = (x1 >= 0 && x1 < W_) ? 1.f : 0.f;
    float w00 = (1.f - dy) * (1.f - dx) * my0 * mx0;
    float w01 = (1.f - dy) * dx * my0 * mx1;
    float w10 = dy * (1.f - dx) * my1 * mx0;
    float w11 = dy * dx * my1 * mx1;
    int y0c = min(max(y0, 0), H_ - 1), y1c = min(max(y1, 0), H_ - 1);
    int x0c = min(max(x0, 0), W_ - 1), x1c = min(max(x1, 0), W_ - 1);
    const short* p00 = xtb + (((y0c << 6) + x0c) << 7);
    const short* p01 = xtb + (((y0c << 6) + x1c) << 7);
    const short* p10 = xtb + (((y1c << 6) + x0c) << 7);
    const short* p11 = xtb + (((y1c << 6) + x1c) << 7);

#pragma unroll
    for (int s = 0; s < 4; ++s) {
      int c0 = (s << 5) + (q << 3);
      short8_t v00 = *(const short8_t*)(p00 + c0);
      short8_t v01 = *(const short8_t*)(p01 + c0);
      short8_t v10 = *(const short8_t*)(p10 + c0);
      short8_t v11 = *(const short8_t*)(p11 + c0);
      short8_t sf;
#pragma unroll
      for (int j = 0; j < 8; ++j) {
        float v = w00 * bf2f(v00[j]) + w01 * bf2f(v01[j]) +
                  w10 * bf2f(v10[j]) + w11 * bf2f(v11[j]);
        sf[j] = bf16r(v);
      }
      int kk = kt * 128 + c0;
      const short* wp = w_bt + fr * CK2_ + kk;
#pragma unroll
      for (int nf = 0; nf < 8; ++nf) {
        short8_t wf = *(const short8_t*)(wp + nf * 16 * CK2_);
        acc[nf] = __builtin_amdgcn_mfma_f32_16x16x32_bf16(wf, sf, acc[nf], 0, 0, 0);
      }
    }
  }

  // epilogue: D[o][pos], o = nf*16 + q*4 + r, pos col = fr -> coalesced
  float* ob = out + ((long)b * O_ * HW_) + (ho << 6) + wo_base + fr;
#pragma unroll
  for (int nf = 0; nf < 8; ++nf) {
#pragma unroll
    for (int r = 0; r < 4; ++r) {
      ob[(((nf << 4) + (q << 2) + r) << 12)] = acc[nf][r];
    }
  }
}

extern "C" void kernel_launch(void* const* d_in, const int* in_sizes, int n_in,
                              void* d_out, int out_size, void* d_ws, size_t ws_size,
                              hipStream_t stream) {
  const float* x     = (const float*)d_in[0];
  const float* w_off = (const float*)d_in[1];
  const float* b_off = (const float*)d_in[2];
  const float* w     = (const float*)d_in[3];
  float* out = (float*)d_out;

  short* w_bt = (short*)d_ws;                                   // 294912 B
  short* w_ot = (short*)((char*)d_ws + 294912);                 // 73728 B
  short* x_t  = (short*)((char*)d_ws + 294912 + 73728);         // 8388608 B

  prep_w_kernel<<<(O_ * CK2_ + 255) / 256, 256, 0, stream>>>(w, w_bt);
  prep_woff_kernel<<<(32 * CK2_ + 255) / 256, 256, 0, stream>>>(w_off, w_ot);
  prep_xt_kernel<<<512, 256, 0, stream>>>(x, x_t);
  fused_deform_kernel<<<(B_ * HW_) / 16, 64, 0, stream>>>(x_t, w_ot, b_off, w_bt, out);
}